// Round 15
// baseline (107.360 us; speedup 1.0000x reference)
//
#include <hip/hip_runtime.h>

// PiecewiseSparseMLP: B=262144 rows, K=32 experts (10 -> 20 -> 1), distance-softmax gating.
// Round 15: R14 (2 row-tiles interleaved in the pair loop, shared A-frag/w2 reads) +
// R11's gx pre-exchange restored for BOTH tiles (deletes all 64 per-pair cross-half
// shuffles + their lgkm waits from the critical path; R11 A/B measured ~5us for this)
// + b2 folded into the gating loop. The +32 VGPR cost of gx[2][16] is funded by reading
// w2 as immediately-consumed v2f (b64) loads (12 b64 ~= 6 b128 LDS cycles, -20 live regs).
// Proven-stable pattern kept: block=512, launch_bounds(512,4)=cap 128, `unroll 2`,
// statically-indexed register arrays only (R8/R9 spill lessons).

#define KX 32
#define DIN 10
#define DH 20
#define BLOCK 512
#define WPB 8   // waves per block
#define TPW 2   // row-tiles per wave (interleaved)

typedef short bf16x8 __attribute__((ext_vector_type(8)));
typedef float f32x16 __attribute__((ext_vector_type(16)));
typedef float v2f    __attribute__((ext_vector_type(2)));

#define ZERO16 {0.f,0.f,0.f,0.f, 0.f,0.f,0.f,0.f, 0.f,0.f,0.f,0.f, 0.f,0.f,0.f,0.f}

__device__ inline unsigned short f2bf(float f) {   // fp32 -> bf16 RNE
    unsigned int u = __float_as_uint(f);
    unsigned int r = u + 0x7fffu + ((u >> 16) & 1u);
    return (unsigned short)(r >> 16);
}

union BFU { bf16x8 v; unsigned short s[8]; };

__global__ __launch_bounds__(BLOCK, 4) void moe_kernel(
    const float* __restrict__ x,      // [B,10]
    const float* __restrict__ W1,     // [32,20,10]
    const float* __restrict__ b1,     // [32,20]
    const float* __restrict__ W2,     // [32,1,20]
    const float* __restrict__ b2,     // [32]
    const float* __restrict__ proto,  // [32,10]
    float* __restrict__ out,          // [B]
    int B)
{
    __shared__ bf16x8 s_af[KX * 40];   // A-frags: [e][kslice*20 + h] (20 KB)
    __shared__ float  s_w2[KX * 24];   // [e][half*12 + reg] W2 compacted C-reg order (3 KB)
    __shared__ bf16x8 s_pf[64];        // proto A-frag (1 KB)
    __shared__ float  s_pn2[32];       // ||proto||^2 in [half*16+reg] order
    __shared__ float  s_b2c[32];       // b2 in [half*16+reg] order

    const int tid = threadIdx.x;

    // ---- build LDS tables (shared by all 8 waves, amortized over 2 tiles/wave) ----
    for (int idx = tid; idx < KX * 40; idx += BLOCK) {
        const int e = idx / 40, rem = idx - e * 40;
        const int ks = rem / 20, h = rem - ks * 20;   // k-slice, hidden index
        BFU u;
#pragma unroll
        for (int j = 0; j < 8; ++j) {
            const int kk = ks * 8 + j;
            float v = 0.f;
            if (kk < DIN) v = W1[(e * DH + h) * DIN + kk];
            else if (kk == DIN) v = b1[e * DH + h];   // bias slot (x_ext[10]=1)
            u.s[j] = f2bf(v);
        }
        s_af[idx] = u.v;
    }
    // W2 in compacted C-reg order: reg q of half hf -> m=(q&3)+8*(q>>2)+4*hf ->
    // h=(m&3)+4*(m>>3)+10*((m&4)?1:0); q=10,11 pad (zero).
    for (int idx = tid; idx < KX * 24; idx += BLOCK) {
        const int e = idx / 24, rem = idx - e * 24;
        const int hf = rem / 12, q = rem - hf * 12;
        float v = 0.f;
        if (q < 10) {
            const int m = (q & 3) + 8 * (q >> 2) + 4 * hf;
            const int h = (m & 3) + 4 * (m >> 3) + ((m & 4) ? 10 : 0);
            v = W2[e * DH + h];
        }
        s_w2[idx] = v;
    }
    if (tid < 64) {
        const int m = tid & 31, kb = (tid >> 5) * 8;
        BFU u;
#pragma unroll
        for (int j = 0; j < 8; ++j) {
            const int kk = kb + j;
            u.s[j] = f2bf(kk < DIN ? proto[m * DIN + kk] : 0.f);  // slot 10 = 0
        }
        s_pf[tid] = u.v;
    }
    if (tid < 32) {
        const int hf = tid >> 4, q = tid & 15;
        const int p = (q & 3) + 8 * (q >> 2) + 4 * hf;
        float s = 0.f;
#pragma unroll
        for (int i = 0; i < DIN; ++i) { const float v = proto[p * DIN + i]; s = fmaf(v, v, s); }
        s_pn2[tid] = s;
        s_b2c[tid] = b2[p];
    }
    __syncthreads();

    const int lane = tid & 63;
    const int wave = tid >> 6;
    const int half = lane >> 5;   // k-slice for A/B frags; C-half for epilogue
    const int col  = lane & 31;
    const bf16x8 pfrag = s_pf[lane];
    const f32x16 kZero = ZERO16;

    // A-frag read index for this lane (compacted mapping) — tile-invariant
    const int m = col;
    const bool mvalid = (m & 4) ? (m < 22) : (m < 18);
    const int hidx = (m & 3) + 4 * (m >> 3) + ((m & 4) ? 10 : 0);  // 0..19 when valid
    const int abase = half * 20 + (mvalid ? hidx : 0);

    // ---- per-tile state (statically indexed only) ----
    int    row[TPW];
    bf16x8 xfrag[TPW];
    float  gate[TPW][16], gx[TPW][16];
    float  nsA[TPW], nsB[TPW], dsum[TPW];

#pragma unroll
    for (int t = 0; t < TPW; ++t) {
        row[t] = ((blockIdx.x * WPB + wave) * TPW + t) * 32 + col;
        const int rr = (row[t] < B) ? row[t] : (B - 1);

        // B-frag: x_ext[rr][half*8 .. +7]; slot 10 = 1.0 (bias)
        float xe[8];
        const float* xr = x + (size_t)rr * DIN;
        if (half == 0) {
#pragma unroll
            for (int i = 0; i < 4; ++i) {
                const float2 v = *(const float2*)(xr + 2 * i);
                xe[2 * i] = v.x; xe[2 * i + 1] = v.y;
            }
        } else {
            const float2 v = *(const float2*)(xr + 8);
            xe[0] = v.x; xe[1] = v.y; xe[2] = 1.f;
            xe[3] = 0.f; xe[4] = 0.f; xe[5] = 0.f; xe[6] = 0.f; xe[7] = 0.f;
        }
        BFU xu;
#pragma unroll
        for (int j = 0; j < 8; ++j) xu.s[j] = f2bf(xe[j]);
        xfrag[t] = xu.v;

        // ||x||^2 (fp32): half0 sums its 8, half1 only x[8],x[9]
        float part;
        if (half == 0) {
            part = 0.f;
#pragma unroll
            for (int j = 0; j < 8; ++j) part = fmaf(xe[j], xe[j], part);
        } else {
            part = fmaf(xe[0], xe[0], xe[1] * xe[1]);
        }
        const float xn2 = part + __shfl_xor(part, 32);

        // gating MFMA + gates; fold b2 terms; pre-exchange gx
        const f32x16 dotg = __builtin_amdgcn_mfma_f32_32x32x16_bf16(pfrag, xfrag[t], kZero, 0, 0, 0);
        const float* pn2h = s_pn2 + half * 16;
        const float* b2c  = s_b2c + half * 16;
        float ds = 0.f, na = 0.f;
#pragma unroll
        for (int q = 0; q < 16; ++q) {
            float d2 = fmaf(dotg[q], -2.f, xn2 + pn2h[q]);
            d2 = fmaxf(d2, 0.f);
            const float g = __expf(-__fsqrt_rn(d2));
            gate[t][q] = g;
            ds += g;
            na = fmaf(g, b2c[q], na);
        }
#pragma unroll
        for (int q = 0; q < 16; ++q) gx[t][q] = __shfl_xor(gate[t][q], 32);
        dsum[t] = ds;
        nsA[t] = na;
        nsB[t] = 0.f;
    }

    // ---- expert loop: pairs (elo, elo+4); A-frag + w2 reads shared by both tiles;
    //      no per-pair shuffles (gx combine) ----
#pragma unroll 2
    for (int j = 0; j < 16; ++j) {
        const int elo = (j & 3) + 8 * (j >> 2);
        const int ehi = elo + 4;

        bf16x8 alo = {0, 0, 0, 0, 0, 0, 0, 0};
        bf16x8 ahi = {0, 0, 0, 0, 0, 0, 0, 0};
        if (mvalid) {
            alo = s_af[elo * 40 + abase];
            ahi = s_af[ehi * 40 + abase];
        }
        const v2f* w2lo = (const v2f*)(s_w2 + elo * 24 + half * 12);
        const v2f* w2hi = (const v2f*)(s_w2 + ehi * 24 + half * 12);

#pragma unroll
        for (int t = 0; t < TPW; ++t) {
            const f32x16 clo = __builtin_amdgcn_mfma_f32_32x32x16_bf16(alo, xfrag[t], kZero, 0, 0, 0);
            const f32x16 chi = __builtin_amdgcn_mfma_f32_32x32x16_bf16(ahi, xfrag[t], kZero, 0, 0, 0);

            v2f plov = v2f{0.f, 0.f}, phiv = v2f{0.f, 0.f};
#pragma unroll
            for (int i = 0; i < 6; ++i) {
                v2f cl = __builtin_elementwise_max(v2f{clo[2 * i], clo[2 * i + 1]}, v2f{0.f, 0.f});
                v2f ch = __builtin_elementwise_max(v2f{chi[2 * i], chi[2 * i + 1]}, v2f{0.f, 0.f});
                plov = __builtin_elementwise_fma(cl, w2lo[i], plov);
                phiv = __builtin_elementwise_fma(ch, w2hi[i], phiv);
            }
            const float pplo = plov.x + plov.y;
            const float pphi = phiv.x + phiv.y;

            // half0 lane: own expert = elo (partial pplo), other = ehi (pphi)
            // half1 lane: own expert = ehi (partial pphi), other = elo (pplo)
            const float p_own = half ? pphi : pplo;
            const float p_oth = half ? pplo : pphi;
            nsA[t] = fmaf(gate[t][j], p_own, nsA[t]);
            nsB[t] = fmaf(gx[t][j],   p_oth, nsB[t]);
        }
    }

    // ---- cross-half combine & write (both tiles) ----
#pragma unroll
    for (int t = 0; t < TPW; ++t) {
        float ns = nsA[t] + nsB[t];
        ns += __shfl_xor(ns, 32);
        float ds = dsum[t] + __shfl_xor(dsum[t], 32);
        if (half == 0 && row[t] < B) out[row[t]] = ns / ds;
    }
}

extern "C" void kernel_launch(void* const* d_in, const int* in_sizes, int n_in,
                              void* d_out, int out_size, void* d_ws, size_t ws_size,
                              hipStream_t stream) {
    const float* x     = (const float*)d_in[0];
    const float* W1    = (const float*)d_in[1];
    const float* b1    = (const float*)d_in[2];
    const float* W2    = (const float*)d_in[3];
    const float* b2    = (const float*)d_in[4];
    const float* proto = (const float*)d_in[5];
    float* out = (float*)d_out;

    const int B = out_size;                    // D_OUT = 1
    const int rows_per_block = WPB * TPW * 32; // 8 waves x 2 tiles x 32 rows = 512
    const int grid = (B + rows_per_block - 1) / rows_per_block;
    hipLaunchKernelGGL(moe_kernel, dim3(grid), dim3(BLOCK), 0, stream,
                       x, W1, b1, W2, b2, proto, out, B);
}

// Round 16
// 94.123 us; speedup vs baseline: 1.1406x; 1.1406x over previous
//
#include <hip/hip_runtime.h>

// PiecewiseSparseMLP: B=262144 rows, K=32 experts (10 -> 20 -> 1), distance-softmax gating.
// Round 16: R14 (best known: 2 row-tiles interleaved, shared A-frag/w2 reads, gate[2][16],
// no gx — R15 proved gate+gx together spill at the 128 cap) + ONE register-neutral cut:
// single-value cross-half exchange per pair per tile. Each lane needs only its OWN half's
// pred (half0 lane accumulates elo, half1 lane ehi; final xor-32 add merges), so we
// exchange just the partial the other half is missing: 1 swizzle/pair/tile instead of 2.
// Proven-stable pattern: block=512, launch_bounds(512,4)=cap 128, `unroll 2`, statically
// indexed arrays (R8/R9/R15 spill lessons). grid=512.

#define KX 32
#define DIN 10
#define DH 20
#define BLOCK 512
#define WPB 8   // waves per block
#define TPW 2   // row-tiles per wave (interleaved)

typedef short bf16x8 __attribute__((ext_vector_type(8)));
typedef float f32x16 __attribute__((ext_vector_type(16)));
typedef float v2f    __attribute__((ext_vector_type(2)));

#define ZERO16 {0.f,0.f,0.f,0.f, 0.f,0.f,0.f,0.f, 0.f,0.f,0.f,0.f, 0.f,0.f,0.f,0.f}

__device__ inline unsigned short f2bf(float f) {   // fp32 -> bf16 RNE
    unsigned int u = __float_as_uint(f);
    unsigned int r = u + 0x7fffu + ((u >> 16) & 1u);
    return (unsigned short)(r >> 16);
}

union BFU { bf16x8 v; unsigned short s[8]; };

__global__ __launch_bounds__(BLOCK, 4) void moe_kernel(
    const float* __restrict__ x,      // [B,10]
    const float* __restrict__ W1,     // [32,20,10]
    const float* __restrict__ b1,     // [32,20]
    const float* __restrict__ W2,     // [32,1,20]
    const float* __restrict__ b2,     // [32]
    const float* __restrict__ proto,  // [32,10]
    float* __restrict__ out,          // [B]
    int B)
{
    __shared__ bf16x8 s_af[KX * 40];   // A-frags: [e][kslice*20 + h] (20 KB)
    __shared__ float  s_w2[KX * 24];   // [e][half*12 + reg] W2 compacted C-reg order (3 KB)
    __shared__ bf16x8 s_pf[64];        // proto A-frag (1 KB)
    __shared__ float  s_pn2[32];       // ||proto||^2 in [half*16+reg] order

    const int tid = threadIdx.x;

    // ---- build LDS tables (shared by all 8 waves, amortized over 2 tiles/wave) ----
    for (int idx = tid; idx < KX * 40; idx += BLOCK) {
        const int e = idx / 40, rem = idx - e * 40;
        const int ks = rem / 20, h = rem - ks * 20;   // k-slice, hidden index
        BFU u;
#pragma unroll
        for (int j = 0; j < 8; ++j) {
            const int kk = ks * 8 + j;
            float v = 0.f;
            if (kk < DIN) v = W1[(e * DH + h) * DIN + kk];
            else if (kk == DIN) v = b1[e * DH + h];   // bias slot (x_ext[10]=1)
            u.s[j] = f2bf(v);
        }
        s_af[idx] = u.v;
    }
    // W2 in compacted C-reg order: reg q of half hf -> m=(q&3)+8*(q>>2)+4*hf ->
    // h=(m&3)+4*(m>>3)+10*((m&4)?1:0); q=10,11 pad (zero).
    for (int idx = tid; idx < KX * 24; idx += BLOCK) {
        const int e = idx / 24, rem = idx - e * 24;
        const int hf = rem / 12, q = rem - hf * 12;
        float v = 0.f;
        if (q < 10) {
            const int m = (q & 3) + 8 * (q >> 2) + 4 * hf;
            const int h = (m & 3) + 4 * (m >> 3) + ((m & 4) ? 10 : 0);
            v = W2[e * DH + h];
        }
        s_w2[idx] = v;
    }
    if (tid < 64) {
        const int m = tid & 31, kb = (tid >> 5) * 8;
        BFU u;
#pragma unroll
        for (int j = 0; j < 8; ++j) {
            const int kk = kb + j;
            u.s[j] = f2bf(kk < DIN ? proto[m * DIN + kk] : 0.f);  // slot 10 = 0
        }
        s_pf[tid] = u.v;
    }
    if (tid < 32) {
        const int hf = tid >> 4, q = tid & 15;
        const int p = (q & 3) + 8 * (q >> 2) + 4 * hf;
        float s = 0.f;
#pragma unroll
        for (int i = 0; i < DIN; ++i) { const float v = proto[p * DIN + i]; s = fmaf(v, v, s); }
        s_pn2[tid] = s;
    }
    __syncthreads();

    const int lane = tid & 63;
    const int wave = tid >> 6;
    const int half = lane >> 5;   // k-slice for A/B frags; C-half for epilogue
    const int col  = lane & 31;
    const bf16x8 pfrag = s_pf[lane];
    const f32x16 kZero = ZERO16;

    // A-frag read index for this lane (compacted mapping) — tile-invariant
    const int m = col;
    const bool mvalid = (m & 4) ? (m < 22) : (m < 18);
    const int hidx = (m & 3) + 4 * (m >> 3) + ((m & 4) ? 10 : 0);  // 0..19 when valid
    const int abase = half * 20 + (mvalid ? hidx : 0);

    // ---- per-tile state (statically indexed only) ----
    int    row[TPW];
    bf16x8 xfrag[TPW];
    float  gate[TPW][16];
    float  nsum[TPW], dsum[TPW];

#pragma unroll
    for (int t = 0; t < TPW; ++t) {
        row[t] = ((blockIdx.x * WPB + wave) * TPW + t) * 32 + col;
        const int rr = (row[t] < B) ? row[t] : (B - 1);

        // B-frag: x_ext[rr][half*8 .. +7]; slot 10 = 1.0 (bias)
        float xe[8];
        const float* xr = x + (size_t)rr * DIN;
        if (half == 0) {
#pragma unroll
            for (int i = 0; i < 4; ++i) {
                const float2 v = *(const float2*)(xr + 2 * i);
                xe[2 * i] = v.x; xe[2 * i + 1] = v.y;
            }
        } else {
            const float2 v = *(const float2*)(xr + 8);
            xe[0] = v.x; xe[1] = v.y; xe[2] = 1.f;
            xe[3] = 0.f; xe[4] = 0.f; xe[5] = 0.f; xe[6] = 0.f; xe[7] = 0.f;
        }
        BFU xu;
#pragma unroll
        for (int j = 0; j < 8; ++j) xu.s[j] = f2bf(xe[j]);
        xfrag[t] = xu.v;

        // ||x||^2 (fp32): half0 sums its 8, half1 only x[8],x[9]
        float part;
        if (half == 0) {
            part = 0.f;
#pragma unroll
            for (int j = 0; j < 8; ++j) part = fmaf(xe[j], xe[j], part);
        } else {
            part = fmaf(xe[0], xe[0], xe[1] * xe[1]);
        }
        const float xn2 = part + __shfl_xor(part, 32);

        // gating MFMA + gates
        const f32x16 dotg = __builtin_amdgcn_mfma_f32_32x32x16_bf16(pfrag, xfrag[t], kZero, 0, 0, 0);
        const float* pn2h = s_pn2 + half * 16;
        float ds = 0.f;
#pragma unroll
        for (int q = 0; q < 16; ++q) {
            float d2 = fmaf(dotg[q], -2.f, xn2 + pn2h[q]);
            d2 = fmaxf(d2, 0.f);
            const float g = __expf(-__fsqrt_rn(d2));
            gate[t][q] = g;
            ds += g;
        }
        dsum[t] = ds;
        nsum[t] = 0.f;
    }

    // ---- expert loop: pairs (elo, elo+4); A-frag + w2 reads shared by both tiles;
    //      ONE cross-half exchange per pair per tile ----
#pragma unroll 2
    for (int j = 0; j < 16; ++j) {
        const int elo = (j & 3) + 8 * (j >> 2);
        const int ehi = elo + 4;

        bf16x8 alo = {0, 0, 0, 0, 0, 0, 0, 0};
        bf16x8 ahi = {0, 0, 0, 0, 0, 0, 0, 0};
        if (mvalid) {
            alo = s_af[elo * 40 + abase];
            ahi = s_af[ehi * 40 + abase];
        }
        const float4* w4lo = (const float4*)(s_w2 + elo * 24 + half * 12);
        const float4* w4hi = (const float4*)(s_w2 + ehi * 24 + half * 12);
        const float4 wl0 = w4lo[0], wl1 = w4lo[1], wl2 = w4lo[2];
        const float4 wh0 = w4hi[0], wh1 = w4hi[1], wh2 = w4hi[2];
        const float b2own = half ? b2[ehi] : b2[elo];

#pragma unroll
        for (int t = 0; t < TPW; ++t) {
            const f32x16 clo = __builtin_amdgcn_mfma_f32_32x32x16_bf16(alo, xfrag[t], kZero, 0, 0, 0);
            const f32x16 chi = __builtin_amdgcn_mfma_f32_32x32x16_bf16(ahi, xfrag[t], kZero, 0, 0, 0);

            v2f plov = v2f{0.f, 0.f}, phiv = v2f{0.f, 0.f};
            {
                v2f c;
                c = __builtin_elementwise_max(v2f{clo[0],  clo[1]},  v2f{0.f, 0.f});
                plov = __builtin_elementwise_fma(c, v2f{wl0.x, wl0.y}, plov);
                c = __builtin_elementwise_max(v2f{clo[2],  clo[3]},  v2f{0.f, 0.f});
                plov = __builtin_elementwise_fma(c, v2f{wl0.z, wl0.w}, plov);
                c = __builtin_elementwise_max(v2f{clo[4],  clo[5]},  v2f{0.f, 0.f});
                plov = __builtin_elementwise_fma(c, v2f{wl1.x, wl1.y}, plov);
                c = __builtin_elementwise_max(v2f{clo[6],  clo[7]},  v2f{0.f, 0.f});
                plov = __builtin_elementwise_fma(c, v2f{wl1.z, wl1.w}, plov);
                c = __builtin_elementwise_max(v2f{clo[8],  clo[9]},  v2f{0.f, 0.f});
                plov = __builtin_elementwise_fma(c, v2f{wl2.x, wl2.y}, plov);
                c = __builtin_elementwise_max(v2f{clo[10], clo[11]}, v2f{0.f, 0.f});
                plov = __builtin_elementwise_fma(c, v2f{wl2.z, wl2.w}, plov);

                c = __builtin_elementwise_max(v2f{chi[0],  chi[1]},  v2f{0.f, 0.f});
                phiv = __builtin_elementwise_fma(c, v2f{wh0.x, wh0.y}, phiv);
                c = __builtin_elementwise_max(v2f{chi[2],  chi[3]},  v2f{0.f, 0.f});
                phiv = __builtin_elementwise_fma(c, v2f{wh0.z, wh0.w}, phiv);
                c = __builtin_elementwise_max(v2f{chi[4],  chi[5]},  v2f{0.f, 0.f});
                phiv = __builtin_elementwise_fma(c, v2f{wh1.x, wh1.y}, phiv);
                c = __builtin_elementwise_max(v2f{chi[6],  chi[7]},  v2f{0.f, 0.f});
                phiv = __builtin_elementwise_fma(c, v2f{wh1.z, wh1.w}, phiv);
                c = __builtin_elementwise_max(v2f{chi[8],  chi[9]},  v2f{0.f, 0.f});
                phiv = __builtin_elementwise_fma(c, v2f{wh2.x, wh2.y}, phiv);
                c = __builtin_elementwise_max(v2f{chi[10], chi[11]}, v2f{0.f, 0.f});
                phiv = __builtin_elementwise_fma(c, v2f{wh2.z, wh2.w}, phiv);
            }
            const float pplo = plov.x + plov.y;   // this lane's partial of elo's dot
            const float pphi = phiv.x + phiv.y;   // this lane's partial of ehi's dot

            // Each lane needs only its OWN half's pred (half0 -> elo, half1 -> ehi).
            // Exchange the partial the other half is missing: one shuffle, not two.
            const float mine   = half ? pphi : pplo;
            const float theirs = half ? pplo : pphi;
            const float recv   = __shfl_xor(theirs, 32);
            const float pred   = mine + recv + b2own;
            nsum[t] = fmaf(gate[t][j], pred, nsum[t]);
        }
    }

    // ---- cross-half combine & write (both tiles) ----
#pragma unroll
    for (int t = 0; t < TPW; ++t) {
        float ns = nsum[t] + __shfl_xor(nsum[t], 32);
        float ds = dsum[t] + __shfl_xor(dsum[t], 32);
        if (half == 0 && row[t] < B) out[row[t]] = ns / ds;
    }
}

extern "C" void kernel_launch(void* const* d_in, const int* in_sizes, int n_in,
                              void* d_out, int out_size, void* d_ws, size_t ws_size,
                              hipStream_t stream) {
    const float* x     = (const float*)d_in[0];
    const float* W1    = (const float*)d_in[1];
    const float* b1    = (const float*)d_in[2];
    const float* W2    = (const float*)d_in[3];
    const float* b2    = (const float*)d_in[4];
    const float* proto = (const float*)d_in[5];
    float* out = (float*)d_out;

    const int B = out_size;                    // D_OUT = 1
    const int rows_per_block = WPB * TPW * 32; // 8 waves x 2 tiles x 32 rows = 512
    const int grid = (B + rows_per_block - 1) / rows_per_block;
    hipLaunchKernelGGL(moe_kernel, dim3(grid), dim3(BLOCK), 0, stream,
                       x, W1, b1, W2, b2, proto, out, B);
}